// Round 5
// baseline (350.228 us; speedup 1.0000x reference)
//
#include <hip/hip_runtime.h>
#include <math.h>

#define B_ 2
#define S_ 2048
#define D_ 1024
#define H_ 16
#define DK_ 64

typedef __attribute__((ext_vector_type(8))) short bf16x8;
typedef __attribute__((ext_vector_type(4))) float f32x4;
typedef __attribute__((ext_vector_type(4))) int i32x4;
typedef __attribute__((ext_vector_type(4))) unsigned int u32x4;

#define MFMA16(a, b, c) __builtin_amdgcn_mfma_f32_16x16x32_bf16((a), (b), (c), 0, 0, 0)

#define ASYNC16(g, l)                                                          \
    __builtin_amdgcn_global_load_lds(                                          \
        (const __attribute__((address_space(1))) void*)(g),                    \
        (__attribute__((address_space(3))) void*)(l), 16, 0, 0)

#define LOG2E 1.4426950408889634f

__device__ __forceinline__ unsigned short f2bf(float x) {
    unsigned int u = __float_as_uint(x);
    unsigned int r = (u + 0x7fffu + ((u >> 16) & 1u)) >> 16;
    return (unsigned short)r;
}

// ---------------------------------------------------------------------------
// pack: fp32 -> bf16 (plain), z selects tensor.
// ---------------------------------------------------------------------------
__global__ __launch_bounds__(256)
void pack_all(const float* __restrict__ q, const float* __restrict__ k,
              const float* __restrict__ v, const float* __restrict__ wq,
              const float* __restrict__ wk, const float* __restrict__ wv,
              const float* __restrict__ wo, unsigned short* __restrict__ ws0)
{
    const int z = blockIdx.z;
    const size_t IN = 4194304, WT = 1048576;
    const float* in;
    unsigned short* dst;
    int n;
    switch (z) {
        case 0: in = q;  dst = ws0;            n = (int)IN; break;
        case 1: in = k;  dst = ws0 + IN;       n = (int)IN; break;
        case 2: in = v;  dst = ws0 + 2*IN;     n = (int)IN; break;
        case 3: in = wq; dst = ws0 + 3*IN;          n = (int)WT; break;
        case 4: in = wk; dst = ws0 + 3*IN + WT;     n = (int)WT; break;
        case 5: in = wv; dst = ws0 + 3*IN + 2*WT;   n = (int)WT; break;
        default:in = wo; dst = ws0 + 3*IN + 3*WT;   n = (int)WT; break;
    }
    const int n4 = n >> 2;
    const int stride = gridDim.x * blockDim.x;
    for (int i = blockIdx.x * blockDim.x + threadIdx.x; i < n4; i += stride) {
        float4 x = ((const float4*)in)[i];
        ushort4 hv;
        hv.x = f2bf(x.x); hv.y = f2bf(x.y); hv.z = f2bf(x.z); hv.w = f2bf(x.w);
        ((ushort4*)dst)[i] = hv;
    }
}

// ---------------------------------------------------------------------------
// Plain bf16 GEMM core: acc += A(M,K) . B(N,K)^T.  128x128 tile, BK=64,
// 256 thr, 128B LDS rows with XOR-8 chunk swizzle (0-conflict verified).
// ---------------------------------------------------------------------------
__device__ __forceinline__ void gemm_core(
    const unsigned short* __restrict__ A, const unsigned short* __restrict__ B,
    unsigned short* As, unsigned short* Bs, int m0, int n0, f32x4 (&acc)[4][4])
{
    const int tid  = threadIdx.x;
    const int w    = tid >> 6;
    const int lane = tid & 63;
    const int rA   = lane & 15;
    const int quad = lane >> 4;
    const int wm   = (w & 1) * 64;
    const int wn   = (w >> 1) * 64;

#pragma unroll 1
    for (int k0 = 0; k0 < 1024; k0 += 64) {
        __syncthreads();
#pragma unroll
        for (int i = 0; i < 4; ++i) {
            const int c   = i * 256 + tid;
            const int row = c >> 3;
            const int g   = (c & 7) ^ (row & 7);
            ASYNC16(A + (size_t)(m0 + row) * 1024 + k0 + g * 8,
                    As + (size_t)(i * 256 + w * 64) * 8);
            ASYNC16(B + (size_t)(n0 + row) * 1024 + k0 + g * 8,
                    Bs + (size_t)(i * 256 + w * 64) * 8);
        }
        __syncthreads();
#pragma unroll
        for (int ks = 0; ks < 2; ++ks) {
            bf16x8 a[4], bb[4];
#pragma unroll
            for (int mt = 0; mt < 4; ++mt) {
                const int row = wm + mt * 16 + rA;
                a[mt] = *(const bf16x8*)&As[row * 64 + (((ks * 4 + quad) ^ (row & 7)) * 8)];
            }
#pragma unroll
            for (int nt = 0; nt < 4; ++nt) {
                const int row = wn + nt * 16 + rA;
                bb[nt] = *(const bf16x8*)&Bs[row * 64 + (((ks * 4 + quad) ^ (row & 7)) * 8)];
            }
#pragma unroll
            for (int mt = 0; mt < 4; ++mt)
#pragma unroll
                for (int nt = 0; nt < 4; ++nt)
                    acc[mt][nt] = MFMA16(a[mt], bb[nt], acc[mt][nt]);
        }
    }
}

// QKV projections.  q,k -> (b,h,s,dk); v -> (b,h,dk,s).
// q pre-scaled by 0.125*log2(e) so attention uses exp2 with no extra mul.
__global__ __launch_bounds__(256)
void gemm_qkv(const unsigned short* __restrict__ ws0,
              const float* __restrict__ bq, const float* __restrict__ bk,
              const float* __restrict__ bv,
              unsigned short* __restrict__ qbuf, unsigned short* __restrict__ kbuf,
              unsigned short* __restrict__ vtbuf)
{
    __shared__ unsigned short As[128 * 64];
    __shared__ unsigned short Bs[128 * 64];
    const size_t IN = 4194304, WT = 1048576;
    const int z = blockIdx.z;
    const unsigned short* Ap = ws0 + (size_t)z * IN;
    const unsigned short* Bp = ws0 + 3 * IN + (size_t)z * WT;
    const float* bias = (z == 0) ? bq : (z == 1) ? bk : bv;
    unsigned short* dst = (z == 0) ? qbuf : (z == 1) ? kbuf : vtbuf;

    const int m0 = blockIdx.y * 128;
    const int n0 = blockIdx.x * 128;
    f32x4 acc[4][4] = {};
    gemm_core(Ap, Bp, As, Bs, m0, n0, acc);

    const int tid = threadIdx.x, w = tid >> 6, lane = tid & 63;
    const int quad = lane >> 4, col = lane & 15;
    const int wm = (w & 1) * 64, wn = (w >> 1) * 64;
    const float qscale = (z == 0) ? (0.125f * LOG2E) : 1.0f;
#pragma unroll
    for (int mt = 0; mt < 4; ++mt)
#pragma unroll
        for (int nt = 0; nt < 4; ++nt) {
            f32x4 v = acc[mt][nt];
#pragma unroll
            for (int r = 0; r < 4; ++r) {
                const int m = m0 + wm + mt * 16 + quad * 4 + r;
                const int n = n0 + wn + nt * 16 + col;
                const float val = (v[r] + bias[n]) * qscale;
                const int bb = m >> 11, ss = m & 2047;
                const int hh = n >> 6, dd = n & 63;
                if (z == 2)
                    dst[((size_t)(bb * 16 + hh) * 64 + dd) * 2048 + ss] = f2bf(val);
                else
                    dst[((size_t)(bb * 16 + hh) * 2048 + ss) * 64 + dd] = f2bf(val);
            }
        }
}

// Output projection: out = ctx(bf16) . Wo^T + bo, fp32 out.
__global__ __launch_bounds__(256)
void gemm_out(const unsigned short* __restrict__ Actx,
              const unsigned short* __restrict__ Bwo,
              const float* __restrict__ bias, float* __restrict__ out)
{
    __shared__ unsigned short As[128 * 64];
    __shared__ unsigned short Bs[128 * 64];
    const int m0 = blockIdx.y * 128;
    const int n0 = blockIdx.x * 128;
    f32x4 acc[4][4] = {};
    gemm_core(Actx, Bwo, As, Bs, m0, n0, acc);

    const int tid = threadIdx.x, w = tid >> 6, lane = tid & 63;
    const int quad = lane >> 4, col = lane & 15;
    const int wm = (w & 1) * 64, wn = (w >> 1) * 64;
#pragma unroll
    for (int mt = 0; mt < 4; ++mt)
#pragma unroll
        for (int nt = 0; nt < 4; ++nt) {
            f32x4 v = acc[mt][nt];
#pragma unroll
            for (int r = 0; r < 4; ++r) {
                const int m = m0 + wm + mt * 16 + quad * 4 + r;
                const int n = n0 + wn + nt * 16 + col;
                out[(size_t)m * 1024 + n] = v[r] + bias[n];
            }
        }
}

// ---------------------------------------------------------------------------
// Flash attention, S^T formulation: S^T = K.Q^T so each lane's scores all
// belong to one q=col; P stays in registers (cross-lane repack via
// ds_bpermute), l accumulated by a ones-MFMA, O^T = V^T.P^T.
// 512 thr = 8 waves, Q-tile 128 (16 q/wave), K-tile 64 double-buffered.
// ---------------------------------------------------------------------------
__global__ __launch_bounds__(512, 4)
void attn_mfma(const unsigned short* __restrict__ qbuf,
               const unsigned short* __restrict__ kbuf,
               const unsigned short* __restrict__ vtbuf,
               const float* __restrict__ posr, const int* __restrict__ mask,
               unsigned short* __restrict__ ctxb)
{
    __shared__ unsigned short Ks[2][64 * 64];
    __shared__ unsigned short Vts[2][64 * 64];

    const int tid  = threadIdx.x;
    const int w    = tid >> 6;          // wave 0..7
    const int lane = tid & 63;
    const int quad = lane >> 4;
    const int col  = lane & 15;
    const int q0   = blockIdx.x * 128;
    const int h    = blockIdx.y;
    const int b    = blockIdx.z;
    const int wq   = w * 16;

    const size_t headoff = (size_t)(b * 16 + h) * 2048 * 64;
    const unsigned short* Qh  = qbuf + headoff + (size_t)q0 * 64;
    const unsigned short* Kh  = kbuf + headoff;
    const unsigned short* Vth = vtbuf + headoff;

    const int srow = tid >> 3;
    const int sg   = (tid & 7) ^ (srow & 7);

    // Q fragment (B-layout: n=col, k=ks*32+quad*8+j) straight from global
    bf16x8 qf[2];
#pragma unroll
    for (int ks = 0; ks < 2; ++ks)
        qf[ks] = *(const bf16x8*)&Qh[(size_t)(wq + col) * 64 + ks * 32 + quad * 8];

    // stage tile 0
    ASYNC16(Kh + (size_t)srow * 64 + sg * 8,    &Ks[0][(size_t)(w * 64) * 8]);
    ASYNC16(Vth + (size_t)srow * 2048 + sg * 8, &Vts[0][(size_t)(w * 64) * 8]);

    f32x4 O[4] = {};
    f32x4 lacc = {};
    const u32x4 onesu = {0x3F803F80u, 0x3F803F80u, 0x3F803F80u, 0x3F803F80u};
    const bf16x8 ones = __builtin_bit_cast(bf16x8, onesu);

    const float* prq = posr + ((size_t)b * 2048 + (q0 + wq + col)) * 2048;
    const int*  mrow = mask + (size_t)b * 2048;

    const int s0 = (quad & 1) * 32 + col;   // src lane for P-frag regs j0..3
    const int s1 = s0 + 16;                 // src lane for j4..7
    const bool hi = (quad & 2) != 0;        // selects 16-block 2ks+1

#pragma unroll 1
    for (int t = 0; t < 32; ++t) {
        __syncthreads();                    // tile t staged, all done with t-1
        const int bb = t & 1;
        const int k0 = t * 64;
        if (t + 1 < 32) {
            const int kn = k0 + 64;
            ASYNC16(Kh + (size_t)(kn + srow) * 64 + sg * 8,   &Ks[bb ^ 1][(size_t)(w * 64) * 8]);
            ASYNC16(Vth + (size_t)srow * 2048 + kn + sg * 8,  &Vts[bb ^ 1][(size_t)(w * 64) * 8]);
        }

        // posr/mask: lane's 16 scores are k = k0 + mt*16 + quad*4 + r, q=col
        f32x4 pr4[4];
        i32x4 mk4[4];
#pragma unroll
        for (int mt = 0; mt < 4; ++mt) {
            pr4[mt] = *(const f32x4*)&prq[k0 + mt * 16 + quad * 4];
            mk4[mt] = *(const i32x4*)&mrow[k0 + mt * 16 + quad * 4];
        }

        // ---- S^T = K.Q^T :  D[m=k-row][n=q] ----
        f32x4 sc[4] = {};
#pragma unroll
        for (int ks = 0; ks < 2; ++ks) {
#pragma unroll
            for (int mt = 0; mt < 4; ++mt) {
                const int row = mt * 16 + col;
                const bf16x8 kb = *(const bf16x8*)
                    &Ks[bb][row * 64 + (((ks * 4 + quad) ^ (col & 7)) * 8)];
                sc[mt] = MFMA16(kb, qf[ks], sc[mt]);
            }
        }

        // ---- p = exp2(s' + pr*log2e), mask, pack to bf16 pairs (trunc) ----
        unsigned int pk[4][2];
#pragma unroll
        for (int mt = 0; mt < 4; ++mt) {
            float p[4];
#pragma unroll
            for (int r = 0; r < 4; ++r) {
                const float t2 = fmaf(pr4[mt][r], LOG2E, sc[mt][r]);
                const float pe = __builtin_amdgcn_exp2f(t2);
                p[r] = mk4[mt][r] ? pe : 0.f;
            }
            pk[mt][0] = __builtin_amdgcn_perm(__float_as_uint(p[1]),
                                              __float_as_uint(p[0]), 0x07060302u);
            pk[mt][1] = __builtin_amdgcn_perm(__float_as_uint(p[3]),
                                              __float_as_uint(p[2]), 0x07060302u);
        }

        // ---- P^T register repack (C-layout -> B-layout) + PV + l ----
#pragma unroll
        for (int ks = 0; ks < 2; ++ks) {
            const unsigned int a0 = (unsigned int)__shfl((int)pk[2 * ks][0],     s0);
            const unsigned int a1 = (unsigned int)__shfl((int)pk[2 * ks][1],     s0);
            const unsigned int b0 = (unsigned int)__shfl((int)pk[2 * ks + 1][0], s0);
            const unsigned int b1 = (unsigned int)__shfl((int)pk[2 * ks + 1][1], s0);
            const unsigned int c0 = (unsigned int)__shfl((int)pk[2 * ks][0],     s1);
            const unsigned int c1 = (unsigned int)__shfl((int)pk[2 * ks][1],     s1);
            const unsigned int d0 = (unsigned int)__shfl((int)pk[2 * ks + 1][0], s1);
            const unsigned int d1 = (unsigned int)__shfl((int)pk[2 * ks + 1][1], s1);
            u32x4 bu;
            bu[0] = hi ? b0 : a0;
            bu[1] = hi ? b1 : a1;
            bu[2] = hi ? d0 : c0;
            bu[3] = hi ? d1 : c1;
            const bf16x8 pb = __builtin_bit_cast(bf16x8, bu);

            lacc = MFMA16(ones, pb, lacc);
#pragma unroll
            for (int dt = 0; dt < 4; ++dt) {
                const int row = dt * 16 + col;
                const bf16x8 vb = *(const bf16x8*)
                    &Vts[bb][row * 64 + (((ks * 4 + quad) ^ (col & 7)) * 8)];
                O[dt] = MFMA16(vb, pb, O[dt]);
            }
        }
    }

    // ---- epilogue: ctx[q][h*64+d] = O^T[d][q] / l[q]  (bf16) ----
    const float inv = 1.f / lacc[0];
    const size_t rowoff = ((size_t)b * 2048 + (q0 + wq + col)) * 1024 + h * 64;
#pragma unroll
    for (int dt = 0; dt < 4; ++dt) {
        ushort4 st;
        st.x = f2bf(O[dt][0] * inv);
        st.y = f2bf(O[dt][1] * inv);
        st.z = f2bf(O[dt][2] * inv);
        st.w = f2bf(O[dt][3] * inv);
        *(ushort4*)&ctxb[rowoff + dt * 16 + quad * 4] = st;
    }
}

// ---------------------------------------------------------------------------
extern "C" void kernel_launch(void* const* d_in, const int* in_sizes, int n_in,
                              void* d_out, int out_size, void* d_ws, size_t ws_size,
                              hipStream_t stream) {
    const float* query = (const float*)d_in[0];
    const float* key   = (const float*)d_in[1];
    const float* value = (const float*)d_in[2];
    const int*   mask  = (const int*)  d_in[3];
    const float* posr  = (const float*)d_in[4];
    const float* Wq    = (const float*)d_in[5];
    const float* bq    = (const float*)d_in[6];
    const float* Wk    = (const float*)d_in[7];
    const float* bk    = (const float*)d_in[8];
    const float* Wv    = (const float*)d_in[9];
    const float* bv    = (const float*)d_in[10];
    const float* Wo    = (const float*)d_in[11];
    const float* bo    = (const float*)d_in[12];
    float* out = (float*)d_out;

    unsigned short* ws0   = (unsigned short*)d_ws;
    const size_t IN = 4194304, WT = 1048576;
    unsigned short* qbuf  = ws0 + 4 * IN;
    unsigned short* kbuf  = ws0 + 5 * IN;
    unsigned short* vtbuf = ws0 + 6 * IN;
    unsigned short* ctxb  = ws0 + 7 * IN;
    const unsigned short* wob = ws0 + 3 * IN + 3 * WT;

    pack_all<<<dim3(512, 1, 7), 256, 0, stream>>>(query, key, value, Wq, Wk, Wv, Wo, ws0);

    gemm_qkv<<<dim3(8, 32, 3), 256, 0, stream>>>(ws0, bq, bk, bv, qbuf, kbuf, vtbuf);

    attn_mfma<<<dim3(16, 16, 2), 512, 0, stream>>>(qbuf, kbuf, vtbuf, posr, mask, ctxb);

    gemm_out<<<dim3(8, 32), 256, 0, stream>>>(ctxb, wob, bo, out);
}

// Round 6
// 273.304 us; speedup vs baseline: 1.2815x; 1.2815x over previous
//
#include <hip/hip_runtime.h>
#include <math.h>

#define B_ 2
#define S_ 2048
#define D_ 1024
#define H_ 16
#define DK_ 64

typedef __attribute__((ext_vector_type(8))) short bf16x8;
typedef __attribute__((ext_vector_type(4))) float f32x4;

#define MFMA16(a, b, c) __builtin_amdgcn_mfma_f32_16x16x32_bf16((a), (b), (c), 0, 0, 0)

#define ASYNC16(g, l)                                                          \
    __builtin_amdgcn_global_load_lds(                                          \
        (const __attribute__((address_space(1))) void*)(g),                    \
        (__attribute__((address_space(3))) void*)(l), 16, 0, 0)

#define LOG2E 1.4426950408889634f

__device__ __forceinline__ unsigned short f2bf(float x) {
    unsigned int u = __float_as_uint(x);
    unsigned int r = (u + 0x7fffu + ((u >> 16) & 1u)) >> 16;
    return (unsigned short)r;
}

// ---------------------------------------------------------------------------
// pack: fp32 -> bf16 (plain), z selects tensor.
// ---------------------------------------------------------------------------
__global__ __launch_bounds__(256)
void pack_all(const float* __restrict__ q, const float* __restrict__ k,
              const float* __restrict__ v, const float* __restrict__ wq,
              const float* __restrict__ wk, const float* __restrict__ wv,
              const float* __restrict__ wo, unsigned short* __restrict__ ws0)
{
    const int z = blockIdx.z;
    const size_t IN = 4194304, WT = 1048576;
    const float* in;
    unsigned short* dst;
    int n;
    switch (z) {
        case 0: in = q;  dst = ws0;            n = (int)IN; break;
        case 1: in = k;  dst = ws0 + IN;       n = (int)IN; break;
        case 2: in = v;  dst = ws0 + 2*IN;     n = (int)IN; break;
        case 3: in = wq; dst = ws0 + 3*IN;          n = (int)WT; break;
        case 4: in = wk; dst = ws0 + 3*IN + WT;     n = (int)WT; break;
        case 5: in = wv; dst = ws0 + 3*IN + 2*WT;   n = (int)WT; break;
        default:in = wo; dst = ws0 + 3*IN + 3*WT;   n = (int)WT; break;
    }
    const int n4 = n >> 2;
    const int stride = gridDim.x * blockDim.x;
    for (int i = blockIdx.x * blockDim.x + threadIdx.x; i < n4; i += stride) {
        float4 x = ((const float4*)in)[i];
        ushort4 hv;
        hv.x = f2bf(x.x); hv.y = f2bf(x.y); hv.z = f2bf(x.z); hv.w = f2bf(x.w);
        ((ushort4*)dst)[i] = hv;
    }
}

// ---------------------------------------------------------------------------
// bf16 GEMM core, 512 thr / 8 waves: acc += A(M,K).B(N,K)^T.  128x128 tile,
// BK=64, wave tile 64x32 (2x4 wave grid).  128B LDS rows + XOR-8 swizzle.
// ---------------------------------------------------------------------------
__device__ __forceinline__ void gemm_core512(
    const unsigned short* __restrict__ A, const unsigned short* __restrict__ B,
    unsigned short* As, unsigned short* Bs, int m0, int n0, f32x4 (&acc)[4][2])
{
    const int tid  = threadIdx.x;
    const int w    = tid >> 6;
    const int lane = tid & 63;
    const int rA   = lane & 15;
    const int quad = lane >> 4;
    const int wm   = (w & 1) * 64;
    const int wn   = (w >> 1) * 32;

#pragma unroll 1
    for (int k0 = 0; k0 < 1024; k0 += 64) {
        __syncthreads();
#pragma unroll
        for (int i = 0; i < 2; ++i) {
            const int c   = i * 512 + tid;
            const int row = c >> 3;
            const int g   = (c & 7) ^ (row & 7);
            ASYNC16(A + (size_t)(m0 + row) * 1024 + k0 + g * 8,
                    As + (size_t)(i * 512 + w * 64) * 8);
            ASYNC16(B + (size_t)(n0 + row) * 1024 + k0 + g * 8,
                    Bs + (size_t)(i * 512 + w * 64) * 8);
        }
        __syncthreads();
#pragma unroll
        for (int ks = 0; ks < 2; ++ks) {
            bf16x8 a[4], bb2[2];
#pragma unroll
            for (int mt = 0; mt < 4; ++mt) {
                const int row = wm + mt * 16 + rA;
                a[mt] = *(const bf16x8*)&As[row * 64 + (((ks * 4 + quad) ^ (row & 7)) * 8)];
            }
#pragma unroll
            for (int nt = 0; nt < 2; ++nt) {
                const int row = wn + nt * 16 + rA;
                bb2[nt] = *(const bf16x8*)&Bs[row * 64 + (((ks * 4 + quad) ^ (row & 7)) * 8)];
            }
#pragma unroll
            for (int mt = 0; mt < 4; ++mt)
#pragma unroll
                for (int nt = 0; nt < 2; ++nt)
                    acc[mt][nt] = MFMA16(a[mt], bb2[nt], acc[mt][nt]);
        }
    }
}

// QKV projections.  q,k -> (b,h,s,dk); v -> (b,h,dk,s).
// q pre-scaled by 0.125*log2(e) so attention uses exp2 directly.
__global__ __launch_bounds__(512, 4)
void gemm_qkv(const unsigned short* __restrict__ ws0,
              const float* __restrict__ bq, const float* __restrict__ bk,
              const float* __restrict__ bv,
              unsigned short* __restrict__ qbuf, unsigned short* __restrict__ kbuf,
              unsigned short* __restrict__ vtbuf)
{
    __shared__ unsigned short As[128 * 64];
    __shared__ unsigned short Bs[128 * 64];
    const size_t IN = 4194304, WT = 1048576;
    const int z = blockIdx.z;
    const unsigned short* Ap = ws0 + (size_t)z * IN;
    const unsigned short* Bp = ws0 + 3 * IN + (size_t)z * WT;
    const float* bias = (z == 0) ? bq : (z == 1) ? bk : bv;
    unsigned short* dst = (z == 0) ? qbuf : (z == 1) ? kbuf : vtbuf;

    const int m0 = blockIdx.y * 128;
    const int n0 = blockIdx.x * 128;
    f32x4 acc[4][2] = {};
    gemm_core512(Ap, Bp, As, Bs, m0, n0, acc);

    const int tid = threadIdx.x, w = tid >> 6, lane = tid & 63;
    const int quad = lane >> 4, col = lane & 15;
    const int wm = (w & 1) * 64, wn = (w >> 1) * 32;
    const float qscale = (z == 0) ? (0.125f * LOG2E) : 1.0f;
#pragma unroll
    for (int mt = 0; mt < 4; ++mt)
#pragma unroll
        for (int nt = 0; nt < 2; ++nt) {
            f32x4 v = acc[mt][nt];
#pragma unroll
            for (int r = 0; r < 4; ++r) {
                const int m = m0 + wm + mt * 16 + quad * 4 + r;
                const int n = n0 + wn + nt * 16 + col;
                const float val = (v[r] + bias[n]) * qscale;
                const int bb = m >> 11, ss = m & 2047;
                const int hh = n >> 6, dd = n & 63;
                if (z == 2)
                    dst[((size_t)(bb * 16 + hh) * 64 + dd) * 2048 + ss] = f2bf(val);
                else
                    dst[((size_t)(bb * 16 + hh) * 2048 + ss) * 64 + dd] = f2bf(val);
            }
        }
}

// Output projection: out = ctx(bf16) . Wo^T + bo, fp32 out.
__global__ __launch_bounds__(512, 4)
void gemm_out(const unsigned short* __restrict__ Actx,
              const unsigned short* __restrict__ Bwo,
              const float* __restrict__ bias, float* __restrict__ out)
{
    __shared__ unsigned short As[128 * 64];
    __shared__ unsigned short Bs[128 * 64];
    const int m0 = blockIdx.y * 128;
    const int n0 = blockIdx.x * 128;
    f32x4 acc[4][2] = {};
    gemm_core512(Actx, Bwo, As, Bs, m0, n0, acc);

    const int tid = threadIdx.x, w = tid >> 6, lane = tid & 63;
    const int quad = lane >> 4, col = lane & 15;
    const int wm = (w & 1) * 64, wn = (w >> 1) * 32;
#pragma unroll
    for (int mt = 0; mt < 4; ++mt)
#pragma unroll
        for (int nt = 0; nt < 2; ++nt) {
            f32x4 v = acc[mt][nt];
#pragma unroll
            for (int r = 0; r < 4; ++r) {
                const int m = m0 + wm + mt * 16 + quad * 4 + r;
                const int n = n0 + wn + nt * 16 + col;
                out[(size_t)m * 1024 + n] = v[r] + bias[n];
            }
        }
}

// ---------------------------------------------------------------------------
// Flash attention (round-4 orientation), software-pipelined:
// triple-buffered K/V, per tile: stage(t+1) -> softmax(t)+P-write -> barrier
// -> PV(t) -> posr-prefetch(t+1) -> QK(t+1).  P round-trip latency is
// absorbed by the barrier; staging covered by softmax; posr covered by a
// full tile.  exp2 with q pre-scaled; P packed by truncation, l sums the
// exact stored values.  512 thr = 8 waves, Q-tile 128, 0-conflict swizzle.
// ---------------------------------------------------------------------------
__global__ __launch_bounds__(512, 4)
void attn_mfma(const unsigned short* __restrict__ qbuf,
               const unsigned short* __restrict__ kbuf,
               const unsigned short* __restrict__ vtbuf,
               const float* __restrict__ posr, const int* __restrict__ mask,
               unsigned short* __restrict__ ctxb)
{
    __shared__ unsigned short Ks[3][64 * 64];
    __shared__ unsigned short Vts[3][64 * 64];
    __shared__ unsigned short Ps[128 * 64];

    const int tid  = threadIdx.x;
    const int w    = tid >> 6;          // wave 0..7
    const int lane = tid & 63;
    const int quad = lane >> 4;
    const int col  = lane & 15;
    const int q0   = blockIdx.x * 128;
    const int h    = blockIdx.y;
    const int b    = blockIdx.z;
    const int wq   = w * 16;

    const size_t headoff = (size_t)(b * 16 + h) * 2048 * 64;
    const unsigned short* Qh  = qbuf + headoff + (size_t)q0 * 64;
    const unsigned short* Kh  = kbuf + headoff;
    const unsigned short* Vth = vtbuf + headoff;

    const int srow = tid >> 3;
    const int sg   = (tid & 7) ^ (srow & 7);

    // Q fragments (A-layout: m=col, k=ks*32+quad*8+j) straight from global
    bf16x8 qf[2];
#pragma unroll
    for (int ks = 0; ks < 2; ++ks)
        qf[ks] = *(const bf16x8*)&Qh[(size_t)(wq + col) * 64 + ks * 32 + quad * 8];

    // stage tile 0 into buffer 0
    ASYNC16(Kh + (size_t)srow * 64 + sg * 8,    &Ks[0][(size_t)(w * 64) * 8]);
    ASYNC16(Vth + (size_t)srow * 2048 + sg * 8, &Vts[0][(size_t)(w * 64) * 8]);

    f32x4 O[4] = {};
    float lsum[4] = {0.f, 0.f, 0.f, 0.f};

    const float* prq[4];
#pragma unroll
    for (int r = 0; r < 4; ++r)
        prq[r] = posr + ((size_t)b * 2048 + (q0 + wq + quad * 4 + r)) * 2048;
    const int* mrow = mask + (size_t)b * 2048;

    // posr for tile 0
    float pr[4][4];
#pragma unroll
    for (int r = 0; r < 4; ++r)
#pragma unroll
        for (int nt = 0; nt < 4; ++nt)
            pr[r][nt] = prq[r][nt * 16 + col];

    __syncthreads();                   // tile 0 staged

    // QK(0)
    f32x4 sc[4] = {};
#pragma unroll
    for (int ks = 0; ks < 2; ++ks)
#pragma unroll
        for (int nt = 0; nt < 4; ++nt) {
            const bf16x8 bk = *(const bf16x8*)
                &Ks[0][(nt * 16 + col) * 64 + (((ks * 4 + quad) ^ (col & 7)) * 8)];
            sc[nt] = MFMA16(qf[ks], bk, sc[nt]);
        }

    int bb = 0;
#pragma unroll 1
    for (int t = 0; t < 32; ++t) {
        const int k0 = t * 64;
        const int bn = (bb == 2) ? 0 : bb + 1;

        int mk[4];
#pragma unroll
        for (int nt = 0; nt < 4; ++nt) mk[nt] = mrow[k0 + nt * 16 + col];

        if (t < 31) {                  // stage t+1 into buffer bn
            const int kn = k0 + 64;
            ASYNC16(Kh + (size_t)(kn + srow) * 64 + sg * 8,  &Ks[bn][(size_t)(w * 64) * 8]);
            ASYNC16(Vth + (size_t)srow * 2048 + kn + sg * 8, &Vts[bn][(size_t)(w * 64) * 8]);
        }

        // ---- softmax: p = exp2(sc + pr*log2e); truncate-pack; l exact ----
#pragma unroll
        for (int r = 0; r < 4; ++r) {
            const int rowW = wq + quad * 4 + r;
            const int rsw  = rowW & 7;
#pragma unroll
            for (int nt = 0; nt < 4; ++nt) {
                const float e = __builtin_amdgcn_exp2f(
                    fmaf(pr[r][nt], LOG2E, sc[nt][r]));
                unsigned int u = __float_as_uint(e) & 0xffff0000u;
                u = mk[nt] ? u : 0u;
                lsum[r] += __uint_as_float(u);
                const int kk = nt * 16 + col;
                Ps[rowW * 64 + ((((kk >> 3) ^ rsw)) * 8) + (kk & 7)] =
                    (unsigned short)(u >> 16);
            }
        }

        if (t < 31) __syncthreads();   // publish buffer bn (t+1 staged)

        // ---- PV(t): O += P.V from buffer bb ----
#pragma unroll
        for (int ks = 0; ks < 2; ++ks) {
            const bf16x8 ap = *(const bf16x8*)
                &Ps[(wq + col) * 64 + (((ks * 4 + quad) ^ (col & 7)) * 8)];
#pragma unroll
            for (int nt = 0; nt < 4; ++nt) {
                const bf16x8 vb = *(const bf16x8*)
                    &Vts[bb][(nt * 16 + col) * 64 + (((ks * 4 + quad) ^ (col & 7)) * 8)];
                O[nt] = MFMA16(ap, vb, O[nt]);
            }
        }

        if (t < 31) {
            const int kn = k0 + 64;
            // posr prefetch for t+1 (full tile of latency cover)
#pragma unroll
            for (int r = 0; r < 4; ++r)
#pragma unroll
                for (int nt = 0; nt < 4; ++nt)
                    pr[r][nt] = prq[r][kn + nt * 16 + col];
            // QK(t+1) from buffer bn
#pragma unroll
            for (int nt = 0; nt < 4; ++nt) sc[nt] = (f32x4){0.f, 0.f, 0.f, 0.f};
#pragma unroll
            for (int ks = 0; ks < 2; ++ks)
#pragma unroll
                for (int nt = 0; nt < 4; ++nt) {
                    const bf16x8 bk = *(const bf16x8*)
                        &Ks[bn][(nt * 16 + col) * 64 + (((ks * 4 + quad) ^ (col & 7)) * 8)];
                    sc[nt] = MFMA16(qf[ks], bk, sc[nt]);
                }
        }
        bb = bn;
    }

    // ---- reduce l across the 16 cols ----
#pragma unroll
    for (int r = 0; r < 4; ++r) {
#pragma unroll
        for (int o = 1; o < 16; o <<= 1) lsum[r] += __shfl_xor(lsum[r], o);
    }

    // ---- epilogue: ctx = O / l  (bf16) ----
#pragma unroll
    for (int r = 0; r < 4; ++r) {
        const float inv = 1.f / lsum[r];
        const size_t rowoff = ((size_t)b * 2048 + (q0 + wq + quad * 4 + r)) * 1024 + h * 64;
#pragma unroll
        for (int nt = 0; nt < 4; ++nt)
            ctxb[rowoff + nt * 16 + col] = f2bf(O[nt][r] * inv);
    }
}

// ---------------------------------------------------------------------------
extern "C" void kernel_launch(void* const* d_in, const int* in_sizes, int n_in,
                              void* d_out, int out_size, void* d_ws, size_t ws_size,
                              hipStream_t stream) {
    const float* query = (const float*)d_in[0];
    const float* key   = (const float*)d_in[1];
    const float* value = (const float*)d_in[2];
    const int*   mask  = (const int*)  d_in[3];
    const float* posr  = (const float*)d_in[4];
    const float* Wq    = (const float*)d_in[5];
    const float* bq    = (const float*)d_in[6];
    const float* Wk    = (const float*)d_in[7];
    const float* bk    = (const float*)d_in[8];
    const float* Wv    = (const float*)d_in[9];
    const float* bv    = (const float*)d_in[10];
    const float* Wo    = (const float*)d_in[11];
    const float* bo    = (const float*)d_in[12];
    float* out = (float*)d_out;

    unsigned short* ws0   = (unsigned short*)d_ws;
    const size_t IN = 4194304, WT = 1048576;
    unsigned short* qbuf  = ws0 + 4 * IN;
    unsigned short* kbuf  = ws0 + 5 * IN;
    unsigned short* vtbuf = ws0 + 6 * IN;
    unsigned short* ctxb  = ws0 + 7 * IN;
    const unsigned short* wob = ws0 + 3 * IN + 3 * WT;

    pack_all<<<dim3(512, 1, 7), 256, 0, stream>>>(query, key, value, Wq, Wk, Wv, Wo, ws0);

    gemm_qkv<<<dim3(8, 32, 3), 512, 0, stream>>>(ws0, bq, bk, bv, qbuf, kbuf, vtbuf);

    attn_mfma<<<dim3(16, 16, 2), 512, 0, stream>>>(qbuf, kbuf, vtbuf, posr, mask, ctxb);

    gemm_out<<<dim3(8, 32), 512, 0, stream>>>(ctxb, wob, bo, out);
}